// Round 7
// baseline (105.132 us; speedup 1.0000x reference)
//
#include <hip/hip_runtime.h>
#include <math.h>

#define N 4096
#define D 128
#define BT 128                     // block tile (128x128 per 256-thread block)
#define NT2 (N / BT)               // 32 tile rows
#define NBLK (NT2 * (NT2 + 1) / 2) // 528 lower-triangle tile pairs
#define NG (N / 16)                // 256 row groups of 16

typedef __attribute__((ext_vector_type(8))) short short8;  // 8 x bf16
typedef __attribute__((ext_vector_type(4))) float f32x4;

union frag_u { short8 v; unsigned int u[4]; };

__device__ __forceinline__ unsigned int pack_bf16x2(float a, float b) {
    unsigned int ua = __float_as_uint(a), ub = __float_as_uint(b);
    ua = (ua + 0x7FFFu + ((ua >> 16) & 1u)) >> 16;
    ub = (ub + 0x7FFFu + ((ub >> 16) & 1u)) >> 16;
    return ua | (ub << 16);
}

// Kernel 1: repack O into MFMA-fragment order + compute s[i]=sqrt(1+||o_i||^2).
// Ofrag[(g*4+kk)*64 + lane] = 8 bf16 of O[g*16+(lane&15)][kk*32+(lane>>4)*8 ..]
__global__ __launch_bounds__(256)
void prep_kernel(const float* __restrict__ O,
                 short8* __restrict__ Ofrag,
                 float* __restrict__ s) {
    __shared__ float psum[16][17];
    const int g    = blockIdx.x;          // 16-row group
    const int tid  = threadIdx.x;
    const int kk   = tid >> 6;            // 0..3 (wave = K-chunk)
    const int lane = tid & 63;
    const int r16  = lane & 15;
    const int qd   = lane >> 4;           // 0..3
    const float* src = O + (size_t)(g * 16 + r16) * D + kk * 32 + qd * 8;
    const float4 v0 = *(const float4*)(src);
    const float4 v1 = *(const float4*)(src + 4);
    frag_u f;
    f.u[0] = pack_bf16x2(v0.x, v0.y);
    f.u[1] = pack_bf16x2(v0.z, v0.w);
    f.u[2] = pack_bf16x2(v1.x, v1.y);
    f.u[3] = pack_bf16x2(v1.z, v1.w);
    Ofrag[(g * 4 + kk) * 64 + lane] = f.v;
    psum[kk * 4 + qd][r16] = v0.x * v0.x + v0.y * v0.y + v0.z * v0.z + v0.w * v0.w
                           + v1.x * v1.x + v1.y * v1.y + v1.z * v1.z + v1.w * v1.w;
    __syncthreads();
    if (tid < 16) {
        float acc = 1.0f;
        #pragma unroll
        for (int x = 0; x < 16; x++) acc += psum[x][tid];
        s[g * 16 + tid] = sqrtf(acc);
    }
}

__device__ __forceinline__ float acosh_dist(float B) {
    // clamp branch |B-1|<1e-6 -> 0 (inert here: B >= ~100 for this data)
    if (fabsf(B - 1.0f) < 1e-6f) return 0.0f;
    const float Bc = fmaxf(B, 1.0f);
    return __log2f(Bc + sqrtf(fmaf(Bc, Bc, -1.0f))) * 0.6931471805599453f;
}

// Kernel 2: one 256-thread block per 128x128 lower-triangle tile; each wave
// one 64x64 quadrant (4x4 frag grid, 64 MFMAs, K=128). Frag traffic 8 B/elem.
// tgt read directly in the epilogue (4x64B lines per inst = tgt-minimal).
// Diag blocks: Q00/Q11 per-element masked, Q01 idles, Q10 full.
__global__ __launch_bounds__(256, 2)
void tile_loss_kernel(const short8* __restrict__ Fr,
                      const float* __restrict__ s,
                      const float* __restrict__ tgt,
                      float* __restrict__ partials) {
    __shared__ float wsum[4];

    const int t = blockIdx.x;
    int ti = (int)((sqrtf(8.0f * (float)t + 1.0f) - 1.0f) * 0.5f);
    while ((ti + 1) * (ti + 2) / 2 <= t) ti++;
    while (ti * (ti + 1) / 2 > t) ti--;
    const int tj = t - ti * (ti + 1) / 2;

    const int tid  = threadIdx.x;
    const int wave = tid >> 6;
    const int lane = tid & 63;
    const int quad = lane >> 4;
    const int l16  = lane & 15;
    const int mq   = wave >> 1;               // quadrant row
    const int nq   = wave & 1;                // quadrant col

    const bool diag   = (ti == tj);
    const bool active = !(diag && mq == 0 && nq == 1);   // Q01 of diag: empty
    const bool qdiag  = diag && (mq == nq);              // Q00/Q11: mask j<i

    float lsum = 0.0f;
    if (active) {
        const int ib  = ti * BT + mq * 64;
        const int jb  = tj * BT + nq * 64;
        const int iag = ib >> 4;              // 16-row group index
        const int jag = jb >> 4;

        f32x4 acc[4][4] = {};                 // [m][n]
        #pragma unroll
        for (int kk = 0; kk < 4; kk++) {
            short8 a[4], b[4];
            #pragma unroll
            for (int m = 0; m < 4; m++) a[m] = Fr[((iag + m) * 4 + kk) * 64 + lane];
            #pragma unroll
            for (int n = 0; n < 4; n++) b[n] = Fr[((jag + n) * 4 + kk) * 64 + lane];
            #pragma unroll
            for (int m = 0; m < 4; m++)
                #pragma unroll
                for (int n = 0; n < 4; n++)
                    acc[m][n] = __builtin_amdgcn_mfma_f32_16x16x32_bf16(
                        a[m], b[n], acc[m][n], 0, 0, 0);
        }

        // Epilogue. C/D layout: col = l16, row = quad*4 + reg (m89/m91).
        float sj[4];
        #pragma unroll
        for (int n = 0; n < 4; n++) sj[n] = s[jb + n * 16 + l16];

        #pragma unroll
        for (int m = 0; m < 4; m++) {
            const int i0 = ib + m * 16 + quad * 4;
            float si[4], tv[4][4];
            #pragma unroll
            for (int r = 0; r < 4; r++) {
                si[r] = s[i0 + r];
                const float* trow = tgt + (size_t)(i0 + r) * N + jb;
                #pragma unroll
                for (int n = 0; n < 4; n++)
                    tv[r][n] = trow[n * 16 + l16];
            }
            if (!qdiag) {
                #pragma unroll
                for (int r = 0; r < 4; r++)
                    #pragma unroll
                    for (int n = 0; n < 4; n++) {
                        const float B = fmaf(si[r], sj[n], -acc[m][n][r]);
                        lsum += fabsf(acosh_dist(B) - tv[r][n]);
                    }
            } else {
                #pragma unroll
                for (int r = 0; r < 4; r++) {
                    const int i = i0 + r;
                    #pragma unroll
                    for (int n = 0; n < 4; n++) {
                        const int j = jb + n * 16 + l16;
                        if (j < i) {
                            const float B = fmaf(si[r], sj[n], -acc[m][n][r]);
                            lsum += fabsf(acosh_dist(B) - tv[r][n]);
                        }
                    }
                }
            }
        }
    }

    // Reduce: wave shuffle -> LDS -> one plain store per block.
    #pragma unroll
    for (int off = 32; off > 0; off >>= 1)
        lsum += __shfl_down(lsum, off, 64);
    if (lane == 0) wsum[wave] = lsum;
    __syncthreads();
    if (tid == 0)
        partials[t] = wsum[0] + wsum[1] + wsum[2] + wsum[3];
}

// Kernel 3: reduce the 528 block partials, scale, write the scalar loss.
__global__ __launch_bounds__(256)
void final_reduce_kernel(const float* __restrict__ partials,
                         float* __restrict__ loss) {
    __shared__ float wsum[4];
    const int tid  = threadIdx.x;
    const int wave = tid >> 6;
    const int lane = tid & 63;
    float acc = 0.0f;
    for (int i = tid; i < NBLK; i += 256) acc += partials[i];
    #pragma unroll
    for (int off = 32; off > 0; off >>= 1)
        acc += __shfl_down(acc, off, 64);
    if (lane == 0) wsum[wave] = acc;
    __syncthreads();
    if (tid == 0) {
        const float tot = wsum[0] + wsum[1] + wsum[2] + wsum[3];
        loss[0] = tot * (1.0f / ((float)N * (float)(N - 1)));
    }
}

extern "C" void kernel_launch(void* const* d_in, const int* in_sizes, int n_in,
                              void* d_out, int out_size, void* d_ws, size_t ws_size,
                              hipStream_t stream) {
    const float* O   = (const float*)d_in[0];   // [4096,128] fp32
    const float* tgt = (const float*)d_in[1];   // [4096,4096] fp32
    float* loss = (float*)d_out;                // scalar

    // ws layout: [0,1MB) frag-ordered bf16 O; [1MB,+16KB) s[]; then partials
    short8* Ofrag = (short8*)d_ws;
    float* s        = (float*)((char*)d_ws + (size_t)N * D * 2);
    float* partials = s + N;

    prep_kernel<<<NG, 256, 0, stream>>>(O, Ofrag, s);
    tile_loss_kernel<<<NBLK, 256, 0, stream>>>(Ofrag, s, tgt, partials);
    final_reduce_kernel<<<1, 256, 0, stream>>>(partials, loss);
}